// Round 1
// baseline (2443.072 us; speedup 1.0000x reference)
//
#include <hip/hip_runtime.h>
#include <cstdint>

using u16 = unsigned short;
using u32 = unsigned int;

typedef __bf16    bf16x8 __attribute__((ext_vector_type(8)));
typedef float     f32x4  __attribute__((ext_vector_type(4)));
typedef _Float16  f16x2  __attribute__((ext_vector_type(2)));
typedef _Float16  f16x8  __attribute__((ext_vector_type(8)));

__device__ __forceinline__ u16 f2bf(float f) {
  u32 u = __float_as_uint(f);
  return (u16)((u + 0x7FFFu + ((u >> 16) & 1u)) >> 16);  // RNE
}
__device__ __forceinline__ float bf2f(u16 h) {
  return __uint_as_float(((u32)h) << 16);
}
__device__ __forceinline__ float sigm(float x) {
  return __fdividef(1.f, 1.f + __expf(-x));
}
__device__ __forceinline__ float tanhfast(float x) {
  return 1.f - __fdividef(2.f, __expf(2.f * x) + 1.f);
}

// ---------------- LayerNorm (optionally concat of two 768-wide inputs) -------
// NIT=6 -> D=1536 (concat hid_a|hid_b), NIT=3 -> D=768 (in0 only).
template<int NIT>
__global__ __launch_bounds__(256) void ln_kernel(
    const float* __restrict__ in0, const float* __restrict__ in1,
    const float* __restrict__ g, const float* __restrict__ bt,
    u16* __restrict__ out)
{
  constexpr int D = NIT * 256;
  const int r = blockIdx.x;
  const int tid = threadIdx.x;
  float vals[NIT];
  float s = 0.f, s2 = 0.f;
#pragma unroll
  for (int i = 0; i < NIT; ++i) {
    int idx = tid + i * 256;
    float v = (idx < 768) ? in0[(size_t)r * 768 + idx]
                          : in1[(size_t)r * 768 + idx - 768];
    vals[i] = v; s += v; s2 += v * v;
  }
#pragma unroll
  for (int off = 32; off > 0; off >>= 1) {
    s  += __shfl_xor(s, off);
    s2 += __shfl_xor(s2, off);
  }
  __shared__ float ws1[4], ws2[4];
  int wid = tid >> 6;
  if ((tid & 63) == 0) { ws1[wid] = s; ws2[wid] = s2; }
  __syncthreads();
  s  = ws1[0] + ws1[1] + ws1[2] + ws1[3];
  s2 = ws2[0] + ws2[1] + ws2[2] + ws2[3];
  const float inv = 1.f / (float)D;
  float mean = s * inv;
  float var  = s2 * inv - mean * mean;
  float rs   = rsqrtf(var + 1e-5f);
#pragma unroll
  for (int i = 0; i < NIT; ++i) {
    int idx = tid + i * 256;
    float y = (vals[i] - mean) * rs * g[idx] + bt[idx];
    out[(size_t)r * D + idx] = f2bf(y);
  }
}

// ---------------- weight transpose + convert: out[n*K+k] = in[k*Nin+n] -------
__global__ void transpose_cvt(const float* __restrict__ in, void* __restrict__ out,
                              int K, int Nin, int Nout, int f16out)
{
  int idx = blockIdx.x * 256 + threadIdx.x;
  if (idx >= K * Nout) return;
  int n = idx / K, k = idx - n * K;
  float v = (n < Nin) ? in[(size_t)k * Nin + n] : 0.f;
  if (f16out) ((_Float16*)out)[idx] = (_Float16)v;
  else        ((u16*)out)[idx] = f2bf(v);
}

// ---------------- shared MFMA GEMM core (B pre-transposed to (N,K) bf16) ----
// A rows: r = b*512 + t; conv window handled via j in [0,KW) with row shift
// (j-PL) and per-row validity (t+j-PL in [0,512)). Optional split A (A0|A1).
// EPI: 0 = +bias, relu, f32 store (conv); 1 = +bias, bf16 store (zx);
//      2 = +bias, f32 store cols<20 only (logits).
struct ConvW {
  const u16*   bt[4];
  const float* bias[4];
};

template<int BN, int NT, int EPI>
__device__ __forceinline__ void gemm_core(
    const u16* __restrict__ A0, const u16* __restrict__ A1, int k_split,
    int a_stride, int KW, int PL, int KJ,
    const u16* __restrict__ BT, int Ktot,
    const float* __restrict__ bias,
    float* __restrict__ outF, u16* __restrict__ outB,
    int out_ld, int out_coff, int n_blk)
{
  constexpr int BM = 128, BK = 64, LDA = BK + 8;  // +8 bf16 pad: 144B rows
  __shared__ __attribute__((aligned(16))) u16 As[BM * LDA];
  __shared__ __attribute__((aligned(16))) u16 Bs[BN * LDA];
  const int tid  = threadIdx.x;
  const int wid  = tid >> 6, lane = tid & 63;
  const int l16  = lane & 15, lq = lane >> 4;
  const int m_blk = blockIdx.x * BM;
  const int wm = (wid & 1) * 64;
  const int wn = (wid >> 1) * (BN / 2);

  f32x4 acc[4][NT];
  const f32x4 z4 = {0.f, 0.f, 0.f, 0.f};
#pragma unroll
  for (int mt = 0; mt < 4; ++mt)
#pragma unroll
    for (int nt = 0; nt < NT; ++nt) acc[mt][nt] = z4;

  for (int j = 0; j < KW; ++j) {
    for (int kin = 0; kin < KJ; kin += BK) {
      const int kg = j * KJ + kin;
      __syncthreads();
      // stage A: 128x64 bf16
#pragma unroll
      for (int it = 0; it < 4; ++it) {
        int idx = tid + it * 256;
        int arow = idx >> 3, ac = (idx & 7) * 8;
        int r = m_blk + arow;
        int tt = (r & 511) + j - PL;
        uint4 val = {0u, 0u, 0u, 0u};
        if ((unsigned)tt < 512u) {
          const u16* src; int kl;
          if (kg + ac < k_split) { src = A0; kl = kin + ac; }
          else                   { src = A1; kl = kin + ac - k_split; }
          val = *(const uint4*)(src + (size_t)(r + j - PL) * a_stride + kl);
        }
        *(uint4*)&As[arow * LDA + ac] = val;
      }
      // stage B^T: BNx64 bf16
#pragma unroll
      for (int it = 0; it < NT; ++it) {
        int idx = tid + it * 256;
        int brow = idx >> 3, bc = (idx & 7) * 8;
        *(uint4*)&Bs[brow * LDA + bc] =
            *(const uint4*)(BT + (size_t)(n_blk + brow) * Ktot + kg + bc);
      }
      __syncthreads();
#pragma unroll
      for (int ks = 0; ks < 2; ++ks) {
        bf16x8 af[4], bfr[NT];
#pragma unroll
        for (int mt = 0; mt < 4; ++mt)
          af[mt] = *(const bf16x8*)&As[(wm + mt * 16 + l16) * LDA + ks * 32 + lq * 8];
#pragma unroll
        for (int nt = 0; nt < NT; ++nt)
          bfr[nt] = *(const bf16x8*)&Bs[(wn + nt * 16 + l16) * LDA + ks * 32 + lq * 8];
#pragma unroll
        for (int mt = 0; mt < 4; ++mt)
#pragma unroll
          for (int nt = 0; nt < NT; ++nt)
            acc[mt][nt] = __builtin_amdgcn_mfma_f32_16x16x32_bf16(
                af[mt], bfr[nt], acc[mt][nt], 0, 0, 0);
      }
    }
  }
  // epilogue: D[row][col], col=lane&15, row=(lane>>4)*4+reg  [m89/m91]
#pragma unroll
  for (int mt = 0; mt < 4; ++mt)
#pragma unroll
    for (int nt = 0; nt < NT; ++nt)
#pragma unroll
      for (int i = 0; i < 4; ++i) {
        int row = m_blk + wm + mt * 16 + lq * 4 + i;
        int col = wn + nt * 16 + l16;
        float v = acc[mt][nt][i];
        if (EPI == 0) {
          v += bias[col];
          outF[(size_t)row * out_ld + out_coff + col] = fmaxf(v, 0.f);
        } else if (EPI == 1) {
          v += bias[n_blk + col];
          outB[(size_t)row * out_ld + n_blk + col] = f2bf(v);
        } else {
          int c = n_blk + col;
          if (c < 20) outF[(size_t)row * out_ld + c] = v + bias[c];
        }
      }
}

__global__ __launch_bounds__(256, 2) void gemm_conv_kernel(
    const u16* __restrict__ xln, ConvW cw, float* __restrict__ out)
{
  const int c = blockIdx.y;            // conv id 0..3, KW=c+1, PL=c>>1
  gemm_core<192, 6, 0>(xln, xln, 1 << 30, 1536, c + 1, c >> 1, 1536,
                       cw.bt[c], 1536 * (c + 1), cw.bias[c],
                       out, nullptr, 768, c * 192, 0);
}

__global__ __launch_bounds__(256, 2) void gemm_zx_kernel(
    const u16* __restrict__ cln,
    const u16* __restrict__ btf, const u16* __restrict__ btb,
    const float* __restrict__ bsf, const float* __restrict__ bsb,
    u16* __restrict__ zf, u16* __restrict__ zb)
{
  const int d = blockIdx.z;
  gemm_core<128, 4, 1>(cln, cln, 1 << 30, 768, 1, 0, 768,
                       d ? btb : btf, 768, d ? bsb : bsf,
                       nullptr, d ? zb : zf, 1024, 0, blockIdx.y * 128);
}

__global__ __launch_bounds__(256, 2) void gemm_logits_kernel(
    const u16* __restrict__ hf, const u16* __restrict__ hb,
    const u16* __restrict__ wdT, const float* __restrict__ bd,
    float* __restrict__ logits)
{
  gemm_core<32, 1, 2>(hf, hb, 256, 256, 1, 0, 512, wdT, 512, bd,
                      logits, nullptr, 20, 0, 0);
}

// ---------------- BiLSTM recurrence: 1 workgroup per (batch, dir) -----------
// thread u owns hidden unit u: gate cols u, 256+u, 512+u (in VGPRs, f16) and
// 768+u (o-gate: k<136 in VGPRs, k in [136,256) in LDS, 240B stride = 16*odd
// -> conflict-free b128). h broadcast via LDS double buffer (f16).
__global__ __launch_bounds__(256, 1) void lstm_kernel(
    const u16* __restrict__ zx_f, const u16* __restrict__ zx_b,
    const _Float16* __restrict__ whT_f, const _Float16* __restrict__ whT_b,
    const int* __restrict__ amask,
    u16* __restrict__ hf, u16* __restrict__ hb)
{
  __shared__ __attribute__((aligned(16))) _Float16 wo[256 * 120];   // 60 KB
  __shared__ __attribute__((aligned(16))) _Float16 hbuf[2][256];    // 1 KB
  const int b = blockIdx.x & 63, rev = blockIdx.x >> 6;
  const u16* zx       = rev ? zx_b : zx_f;
  const _Float16* whT = rev ? whT_b : whT_f;
  u16* hout           = rev ? hb : hf;
  const int u = threadIdx.x;

  f16x8 w0[32], w1[32], w2[32], w3h[17];
  const f16x8* p0 = (const f16x8*)(whT + (size_t)u * 256);
  const f16x8* p1 = (const f16x8*)(whT + (size_t)(256 + u) * 256);
  const f16x8* p2 = (const f16x8*)(whT + (size_t)(512 + u) * 256);
  const f16x8* p3 = (const f16x8*)(whT + (size_t)(768 + u) * 256);
#pragma unroll
  for (int q = 0; q < 32; ++q) { w0[q] = p0[q]; w1[q] = p1[q]; w2[q] = p2[q]; }
#pragma unroll
  for (int c = 0; c < 17; ++c) w3h[c] = p3[c];
#pragma unroll
  for (int q = 0; q < 15; ++q)
    *(f16x8*)(wo + u * 120 + q * 8) = p3[17 + q];
  hbuf[0][u] = (_Float16)0.f;

  float cst = 0.f, hst = 0.f, oprev = 0.f;
  const int t0 = rev ? 511 : 0;
  const u16* zr0 = zx + (size_t)(b * 512 + t0) * 1024;
  u16 z0 = zr0[u], z1 = zr0[256 + u], z2 = zr0[512 + u], z3 = zr0[768 + u];
  int mk = amask[b * 512 + t0];
  __syncthreads();

  int cur = 0;
  for (int step = 0; step < 512; ++step) {
    const int t = rev ? 511 - step : step;
    // prefetch next step's zx + mask (hidden behind the dot phase)
    const int sn = step < 511 ? step + 1 : step;
    const int tn = rev ? 511 - sn : sn;
    const u16* zrn = zx + (size_t)(b * 512 + tn) * 1024;
    u16 nz0 = zrn[u], nz1 = zrn[256 + u], nz2 = zrn[512 + u], nz3 = zrn[768 + u];
    int nmk = amask[b * 512 + tn];

    const f16x8* h8p  = (const f16x8*)(&hbuf[cur][0]);
    const f16x8* wo8p = (const f16x8*)(wo + u * 120);
    f16x2 a0 = {0, 0}, a1 = {0, 0}, a2 = {0, 0}, a3 = {0, 0};
#pragma unroll
    for (int q = 0; q < 32; ++q) {
      f16x8 hv = h8p[q];
      f16x8 wv = (q < 17) ? w3h[q] : wo8p[q - 17];
#pragma unroll
      for (int jj = 0; jj < 4; ++jj) {
        f16x2 hp = {hv[2 * jj], hv[2 * jj + 1]};
        f16x2 wa = {w0[q][2 * jj], w0[q][2 * jj + 1]};
        f16x2 wb = {w1[q][2 * jj], w1[q][2 * jj + 1]};
        f16x2 wc = {w2[q][2 * jj], w2[q][2 * jj + 1]};
        f16x2 wdp = {wv[2 * jj], wv[2 * jj + 1]};
        a0 = __builtin_elementwise_fma(wa, hp, a0);
        a1 = __builtin_elementwise_fma(wb, hp, a1);
        a2 = __builtin_elementwise_fma(wc, hp, a2);
        a3 = __builtin_elementwise_fma(wdp, hp, a3);
      }
    }
    float zi  = bf2f(z0) + (float)a0[0] + (float)a0[1];
    float zf_ = bf2f(z1) + (float)a1[0] + (float)a1[1];
    float zg  = bf2f(z2) + (float)a2[0] + (float)a2[1];
    float zo  = bf2f(z3) + (float)a3[0] + (float)a3[1];
    float ig = sigm(zi), fg = sigm(zf_), og = sigm(zo);
    float gg = tanhfast(zg);
    float cn = fg * cst + ig * gg;
    float hn = og * tanhfast(cn);
    if (mk != 0) { cst = cn; hst = hn; oprev = hn; }   // mask uniform per block
    hbuf[cur ^ 1][u] = (_Float16)hst;
    hout[(size_t)(b * 512 + t) * 256 + u] = f2bf(oprev);
    __syncthreads();
    cur ^= 1;
    z0 = nz0; z1 = nz1; z2 = nz2; z3 = nz3; mk = nmk;
  }
}

// ---------------- CRF log-likelihood: 1 wave per batch -----------------------
__global__ __launch_bounds__(64) void crf_kernel(
    const float* __restrict__ logits, const int* __restrict__ targets,
    const int* __restrict__ inputs, const float* __restrict__ trans,
    float* __restrict__ out)
{
  const int b = blockIdx.x, lane = threadIdx.x;
  int slp = 0;
  for (int t = lane; t < 512; t += 64) slp += (inputs[b * 512 + t] != 0) ? 1 : 0;
#pragma unroll
  for (int off = 32; off > 0; off >>= 1) slp += __shfl_xor(slp, off);
  const int seq_len = slp;

  float un = 0.f, bin = 0.f;
  for (int t = lane; t < 512; t += 64) {
    if (t < seq_len)
      un += logits[(size_t)(b * 512 + t) * 20 + targets[b * 512 + t]];
    if (t >= 1 && t < seq_len)
      bin += trans[targets[b * 512 + t - 1] * 20 + targets[b * 512 + t]];
  }
#pragma unroll
  for (int off = 32; off > 0; off >>= 1) {
    un += __shfl_xor(un, off); bin += __shfl_xor(bin, off);
  }

  const int j = (lane < 20) ? lane : 0;
  float tc[20];
#pragma unroll
  for (int i = 0; i < 20; ++i) tc[i] = trans[i * 20 + j];
  float alpha = logits[(size_t)(b * 512) * 20 + j];
  for (int t = 1; t < seq_len; ++t) {
    float emit = logits[(size_t)(b * 512 + t) * 20 + j];
    float tmp[20], mx = -1e30f;
#pragma unroll
    for (int i = 0; i < 20; ++i) {
      float ai = __shfl(alpha, i);
      tmp[i] = ai + tc[i];
      mx = fmaxf(mx, tmp[i]);
    }
    float s = 0.f;
#pragma unroll
    for (int i = 0; i < 20; ++i) s += __expf(tmp[i] - mx);
    alpha = mx + __logf(s) + emit;
  }
  float av = (lane < 20) ? alpha : -1e30f;
  float mx = av;
#pragma unroll
  for (int off = 32; off > 0; off >>= 1) mx = fmaxf(mx, __shfl_xor(mx, off));
  float s = (lane < 20) ? __expf(av - mx) : 0.f;
#pragma unroll
  for (int off = 32; off > 0; off >>= 1) s += __shfl_xor(s, off);
  if (lane == 0) out[b] = un + bin - (mx + __logf(s));
}

// ---------------- host launcher ---------------------------------------------
extern "C" void kernel_launch(void* const* d_in, const int* in_sizes, int n_in,
                              void* d_out, int out_size, void* d_ws, size_t ws_size,
                              hipStream_t stream)
{
  const int*   inputs  = (const int*)d_in[0];
  const int*   amask   = (const int*)d_in[1];
  const int*   targets = (const int*)d_in[2];
  const float* hid_a   = (const float*)d_in[3];
  const float* hid_b   = (const float*)d_in[4];
  const float* ln1_g   = (const float*)d_in[5];
  const float* ln1_b   = (const float*)d_in[6];
  const float* w1 = (const float*)d_in[7];
  const float* b1 = (const float*)d_in[8];
  const float* w2 = (const float*)d_in[9];
  const float* b2 = (const float*)d_in[10];
  const float* w3 = (const float*)d_in[11];
  const float* b3 = (const float*)d_in[12];
  const float* w4 = (const float*)d_in[13];
  const float* b4 = (const float*)d_in[14];
  const float* ln2_g = (const float*)d_in[15];
  const float* ln2_b = (const float*)d_in[16];
  const float* wx_f = (const float*)d_in[17];
  const float* wh_f = (const float*)d_in[18];
  const float* bfv  = (const float*)d_in[19];
  const float* wx_b = (const float*)d_in[20];
  const float* wh_b = (const float*)d_in[21];
  const float* bbv  = (const float*)d_in[22];
  const float* wd   = (const float*)d_in[23];
  const float* bd   = (const float*)d_in[24];
  const float* trans= (const float*)d_in[25];
  (void)in_sizes; (void)n_in; (void)out_size; (void)ws_size;

  char* ws = (char*)d_ws;
  constexpr size_t SZ_XLN  = (size_t)32768 * 1536 * 2;   // bf16 LN1 out
  constexpr size_t SZ_CONV = (size_t)32768 * 768 * 4;    // f32 conv+relu
  constexpr size_t SZ_CLN  = (size_t)32768 * 768 * 2;    // bf16 LN2 out
  u16*   x_ln      = (u16*)(ws + 0);
  float* conv_relu = (float*)(ws + SZ_XLN);
  u16*   conv_ln   = (u16*)(ws + SZ_XLN + SZ_CONV);
  u16*   zx_f      = (u16*)(ws + 0);                     // reuse x_ln region
  u16*   zx_b      = (u16*)(ws + SZ_XLN);                // reuse conv_relu region
  u16*   hfp       = (u16*)(ws + SZ_XLN + SZ_CONV);      // reuse conv_ln region
  u16*   hbp       = hfp + (size_t)32768 * 256;
  size_t off = SZ_XLN + SZ_CONV + SZ_CLN;
  float* logitsB = (float*)(ws + off); off += (size_t)32768 * 20 * 4;
  u16* wT1 = (u16*)(ws + off); off += (size_t)192 * 1536 * 2;
  u16* wT2 = (u16*)(ws + off); off += (size_t)192 * 3072 * 2;
  u16* wT3 = (u16*)(ws + off); off += (size_t)192 * 4608 * 2;
  u16* wT4 = (u16*)(ws + off); off += (size_t)192 * 6144 * 2;
  u16* wxTf = (u16*)(ws + off); off += (size_t)1024 * 768 * 2;
  u16* wxTb = (u16*)(ws + off); off += (size_t)1024 * 768 * 2;
  _Float16* whTf = (_Float16*)(ws + off); off += (size_t)1024 * 256 * 2;
  _Float16* whTb = (_Float16*)(ws + off); off += (size_t)1024 * 256 * 2;
  u16* wdT = (u16*)(ws + off); off += (size_t)32 * 512 * 2;

  auto tcl = [&](const float* in, void* outp, int K, int Nin, int Nout, int f16o) {
    int tot = K * Nout;
    hipLaunchKernelGGL(transpose_cvt, dim3((tot + 255) / 256), dim3(256), 0, stream,
                       in, outp, K, Nin, Nout, f16o);
  };
  tcl(w1, wT1, 1536, 192, 192, 0);
  tcl(w2, wT2, 3072, 192, 192, 0);
  tcl(w3, wT3, 4608, 192, 192, 0);
  tcl(w4, wT4, 6144, 192, 192, 0);
  tcl(wx_f, wxTf, 768, 1024, 1024, 0);
  tcl(wx_b, wxTb, 768, 1024, 1024, 0);
  tcl(wh_f, whTf, 256, 1024, 1024, 1);
  tcl(wh_b, whTb, 256, 1024, 1024, 1);
  tcl(wd, wdT, 512, 20, 32, 0);

  hipLaunchKernelGGL((ln_kernel<6>), dim3(32768), dim3(256), 0, stream,
                     hid_a, hid_b, ln1_g, ln1_b, x_ln);

  ConvW cw;
  cw.bt[0] = wT1; cw.bt[1] = wT2; cw.bt[2] = wT3; cw.bt[3] = wT4;
  cw.bias[0] = b1; cw.bias[1] = b2; cw.bias[2] = b3; cw.bias[3] = b4;
  hipLaunchKernelGGL(gemm_conv_kernel, dim3(256, 4), dim3(256), 0, stream,
                     x_ln, cw, conv_relu);

  hipLaunchKernelGGL((ln_kernel<3>), dim3(32768), dim3(256), 0, stream,
                     conv_relu, conv_relu, ln2_g, ln2_b, conv_ln);

  hipLaunchKernelGGL(gemm_zx_kernel, dim3(256, 8, 2), dim3(256), 0, stream,
                     conv_ln, wxTf, wxTb, bfv, bbv, zx_f, zx_b);

  hipLaunchKernelGGL(lstm_kernel, dim3(128), dim3(256), 0, stream,
                     zx_f, zx_b, whTf, whTb, amask, hfp, hbp);

  hipLaunchKernelGGL(gemm_logits_kernel, dim3(256), dim3(256), 0, stream,
                     hfp, hbp, wdT, bd, logitsB);

  hipLaunchKernelGGL(crf_kernel, dim3(64), dim3(64), 0, stream,
                     logitsB, targets, inputs, trans, (float*)d_out);
}

// Round 2
// 1947.314 us; speedup vs baseline: 1.2546x; 1.2546x over previous
//
#include <hip/hip_runtime.h>
#include <cstdint>

using u16 = unsigned short;
using u32 = unsigned int;

typedef __bf16    bf16x8 __attribute__((ext_vector_type(8)));
typedef float     f32x4  __attribute__((ext_vector_type(4)));
typedef _Float16  f16x2  __attribute__((ext_vector_type(2)));
typedef _Float16  f16x8  __attribute__((ext_vector_type(8)));

__device__ __forceinline__ u16 f2bf(float f) {
  u32 u = __float_as_uint(f);
  return (u16)((u + 0x7FFFu + ((u >> 16) & 1u)) >> 16);  // RNE
}
__device__ __forceinline__ float bf2f(u16 h) {
  return __uint_as_float(((u32)h) << 16);
}
__device__ __forceinline__ float sigm(float x) {
  return __fdividef(1.f, 1.f + __expf(-x));
}
__device__ __forceinline__ float tanhfast(float x) {
  return 1.f - __fdividef(2.f, __expf(2.f * x) + 1.f);
}

// ---------------- LayerNorm (optionally concat of two 768-wide inputs) -------
template<int NIT>
__global__ __launch_bounds__(256) void ln_kernel(
    const float* __restrict__ in0, const float* __restrict__ in1,
    const float* __restrict__ g, const float* __restrict__ bt,
    u16* __restrict__ out)
{
  constexpr int D = NIT * 256;
  const int r = blockIdx.x;
  const int tid = threadIdx.x;
  float vals[NIT];
  float s = 0.f, s2 = 0.f;
#pragma unroll
  for (int i = 0; i < NIT; ++i) {
    int idx = tid + i * 256;
    float v = (idx < 768) ? in0[(size_t)r * 768 + idx]
                          : in1[(size_t)r * 768 + idx - 768];
    vals[i] = v; s += v; s2 += v * v;
  }
#pragma unroll
  for (int off = 32; off > 0; off >>= 1) {
    s  += __shfl_xor(s, off);
    s2 += __shfl_xor(s2, off);
  }
  __shared__ float ws1[4], ws2[4];
  int wid = tid >> 6;
  if ((tid & 63) == 0) { ws1[wid] = s; ws2[wid] = s2; }
  __syncthreads();
  s  = ws1[0] + ws1[1] + ws1[2] + ws1[3];
  s2 = ws2[0] + ws2[1] + ws2[2] + ws2[3];
  const float inv = 1.f / (float)D;
  float mean = s * inv;
  float var  = s2 * inv - mean * mean;
  float rs   = rsqrtf(var + 1e-5f);
#pragma unroll
  for (int i = 0; i < NIT; ++i) {
    int idx = tid + i * 256;
    float y = (vals[i] - mean) * rs * g[idx] + bt[idx];
    out[(size_t)r * D + idx] = f2bf(y);
  }
}

// ---------------- weight transpose + convert: out[n*K+k] = in[k*Nin+n] -------
__global__ void transpose_cvt(const float* __restrict__ in, void* __restrict__ out,
                              int K, int Nin, int Nout, int f16out)
{
  int idx = blockIdx.x * 256 + threadIdx.x;
  if (idx >= K * Nout) return;
  int n = idx / K, k = idx - n * K;
  float v = (n < Nin) ? in[(size_t)k * Nin + n] : 0.f;
  if (f16out) ((_Float16*)out)[idx] = (_Float16)v;
  else        ((u16*)out)[idx] = f2bf(v);
}

// ---------------- shared MFMA GEMM core (B pre-transposed to (N,K) bf16) ----
struct ConvW {
  const u16*   bt[4];
  const float* bias[4];
};

template<int BN, int NT, int EPI>
__device__ __forceinline__ void gemm_core(
    const u16* __restrict__ A0, const u16* __restrict__ A1, int k_split,
    int a_stride, int KW, int PL, int KJ,
    const u16* __restrict__ BT, int Ktot,
    const float* __restrict__ bias,
    float* __restrict__ outF, u16* __restrict__ outB,
    int out_ld, int out_coff, int n_blk)
{
  constexpr int BM = 128, BK = 64, LDA = BK + 8;  // +8 bf16 pad: 144B rows
  __shared__ __attribute__((aligned(16))) u16 As[BM * LDA];
  __shared__ __attribute__((aligned(16))) u16 Bs[BN * LDA];
  const int tid  = threadIdx.x;
  const int wid  = tid >> 6, lane = tid & 63;
  const int l16  = lane & 15, lq = lane >> 4;
  const int m_blk = blockIdx.x * BM;
  const int wm = (wid & 1) * 64;
  const int wn = (wid >> 1) * (BN / 2);

  f32x4 acc[4][NT];
  const f32x4 z4 = {0.f, 0.f, 0.f, 0.f};
#pragma unroll
  for (int mt = 0; mt < 4; ++mt)
#pragma unroll
    for (int nt = 0; nt < NT; ++nt) acc[mt][nt] = z4;

  for (int j = 0; j < KW; ++j) {
    for (int kin = 0; kin < KJ; kin += BK) {
      const int kg = j * KJ + kin;
      __syncthreads();
#pragma unroll
      for (int it = 0; it < 4; ++it) {
        int idx = tid + it * 256;
        int arow = idx >> 3, ac = (idx & 7) * 8;
        int r = m_blk + arow;
        int tt = (r & 511) + j - PL;
        uint4 val = {0u, 0u, 0u, 0u};
        if ((unsigned)tt < 512u) {
          const u16* src; int kl;
          if (kg + ac < k_split) { src = A0; kl = kin + ac; }
          else                   { src = A1; kl = kin + ac - k_split; }
          val = *(const uint4*)(src + (size_t)(r + j - PL) * a_stride + kl);
        }
        *(uint4*)&As[arow * LDA + ac] = val;
      }
#pragma unroll
      for (int it = 0; it < NT; ++it) {
        int idx = tid + it * 256;
        int brow = idx >> 3, bc = (idx & 7) * 8;
        *(uint4*)&Bs[brow * LDA + bc] =
            *(const uint4*)(BT + (size_t)(n_blk + brow) * Ktot + kg + bc);
      }
      __syncthreads();
#pragma unroll
      for (int ks = 0; ks < 2; ++ks) {
        bf16x8 af[4], bfr[NT];
#pragma unroll
        for (int mt = 0; mt < 4; ++mt)
          af[mt] = *(const bf16x8*)&As[(wm + mt * 16 + l16) * LDA + ks * 32 + lq * 8];
#pragma unroll
        for (int nt = 0; nt < NT; ++nt)
          bfr[nt] = *(const bf16x8*)&Bs[(wn + nt * 16 + l16) * LDA + ks * 32 + lq * 8];
#pragma unroll
        for (int mt = 0; mt < 4; ++mt)
#pragma unroll
          for (int nt = 0; nt < NT; ++nt)
            acc[mt][nt] = __builtin_amdgcn_mfma_f32_16x16x32_bf16(
                af[mt], bfr[nt], acc[mt][nt], 0, 0, 0);
      }
    }
  }
#pragma unroll
  for (int mt = 0; mt < 4; ++mt)
#pragma unroll
    for (int nt = 0; nt < NT; ++nt)
#pragma unroll
      for (int i = 0; i < 4; ++i) {
        int row = m_blk + wm + mt * 16 + lq * 4 + i;
        int col = wn + nt * 16 + l16;
        float v = acc[mt][nt][i];
        if (EPI == 0) {
          v += bias[col];
          outF[(size_t)row * out_ld + out_coff + col] = fmaxf(v, 0.f);
        } else if (EPI == 1) {
          v += bias[n_blk + col];
          outB[(size_t)row * out_ld + n_blk + col] = f2bf(v);
        } else {
          int c = n_blk + col;
          if (c < 20) outF[(size_t)row * out_ld + c] = v + bias[c];
        }
      }
}

__global__ __launch_bounds__(256, 2) void gemm_conv_kernel(
    const u16* __restrict__ xln, ConvW cw, float* __restrict__ out)
{
  const int c = blockIdx.y;            // conv id 0..3, KW=c+1, PL=c>>1
  gemm_core<192, 6, 0>(xln, xln, 1 << 30, 1536, c + 1, c >> 1, 1536,
                       cw.bt[c], 1536 * (c + 1), cw.bias[c],
                       out, nullptr, 768, c * 192, 0);
}

__global__ __launch_bounds__(256, 2) void gemm_zx_kernel(
    const u16* __restrict__ cln,
    const u16* __restrict__ btf, const u16* __restrict__ btb,
    const float* __restrict__ bsf, const float* __restrict__ bsb,
    u16* __restrict__ zf, u16* __restrict__ zb)
{
  const int d = blockIdx.z;
  gemm_core<128, 4, 1>(cln, cln, 1 << 30, 768, 1, 0, 768,
                       d ? btb : btf, 768, d ? bsb : bsf,
                       nullptr, d ? zb : zf, 1024, 0, blockIdx.y * 128);
}

__global__ __launch_bounds__(256, 2) void gemm_logits_kernel(
    const u16* __restrict__ hf, const u16* __restrict__ hb,
    const u16* __restrict__ wdT, const float* __restrict__ bd,
    float* __restrict__ logits)
{
  gemm_core<32, 1, 2>(hf, hb, 256, 256, 1, 0, 512, wdT, 512, bd,
                      logits, nullptr, 20, 0, 0);
}

// ---------------- BiLSTM recurrence: 1 workgroup per (batch, dir) -----------
// 512 threads: u = t>>1 (hidden unit), s = t&1 (k-half). Gates i,f,g weight
// slices (128 f16 each = 192 VGPRs) stay in registers (<=256-VGPR VALU cap,
// the R0 spill bug). o-gate weights live in dynamic LDS: 512 rows x 136-f16
// stride (17*16B) so unique ds_read_b128 spread across all bank groups.
// h double-buffered in LDS (2-addr broadcast reads = free 2-way).
__global__ __launch_bounds__(512) void lstm_kernel(
    const u16* __restrict__ zx_f, const u16* __restrict__ zx_b,
    const _Float16* __restrict__ whT_f, const _Float16* __restrict__ whT_b,
    const int* __restrict__ amask,
    u16* __restrict__ hf, u16* __restrict__ hb)
{
  extern __shared__ char smem[];
  _Float16* wo   = (_Float16*)smem;                       // 512*136 f16
  _Float16* hbuf = (_Float16*)(smem + 512 * 136 * 2);     // 2*256 f16
  const int b = blockIdx.x & 63, rev = blockIdx.x >> 6;
  const u16* zx       = rev ? zx_b : zx_f;
  const _Float16* whT = rev ? whT_b : whT_f;
  u16* hout           = rev ? hb : hf;
  const int t = threadIdx.x;
  const int u = t >> 1, s = t & 1;
  const int kb = s * 128;

  // VGPR-resident weights: gates 0(i),1(f),2(g), 16 x f16x8 each
  f16x8 w[3][16];
#pragma unroll
  for (int g = 0; g < 3; ++g) {
    const f16x8* pg = (const f16x8*)(whT + (size_t)(g * 256 + u) * 256 + kb);
#pragma unroll
    for (int q = 0; q < 16; ++q) w[g][q] = pg[q];
  }
  // o-gate slice -> LDS row t
  {
    const f16x8* po = (const f16x8*)(whT + (size_t)(768 + u) * 256 + kb);
    _Float16* row = wo + t * 136;
#pragma unroll
    for (int c = 0; c < 16; ++c) *(f16x8*)(row + 8 * c) = po[c];
  }
  if (t < 256) hbuf[t] = (_Float16)0.f;

  float cst = 0.f, hst = 0.f, oprev = 0.f;
  const int t0 = rev ? 511 : 0;
  const u16* zr0 = zx + (size_t)(b * 512 + t0) * 1024;
  u16 z0 = zr0[u], z1 = zr0[256 + u], z2 = zr0[512 + u], z3 = zr0[768 + u];
  int mk = amask[b * 512 + t0];
  __syncthreads();

  int cur = 0;
  for (int step = 0; step < 512; ++step) {
    const int t_cur = rev ? 511 - step : step;
    // prefetch next step's zx + mask
    const int sn = step < 511 ? step + 1 : step;
    const int tn = rev ? 511 - sn : sn;
    const u16* zrn = zx + (size_t)(b * 512 + tn) * 1024;
    u16 nz0 = zrn[u], nz1 = zrn[256 + u], nz2 = zrn[512 + u], nz3 = zrn[768 + u];
    int nmk = amask[b * 512 + tn];

    const _Float16* hc = hbuf + cur * 256 + kb;
    const _Float16* wr = wo + t * 136;
    f16x2 a0 = {0, 0}, a1 = {0, 0}, a2 = {0, 0}, a3 = {0, 0};
#pragma unroll
    for (int c = 0; c < 16; ++c) {
      f16x8 hv = *(const f16x8*)(hc + 8 * c);
      f16x8 ov = *(const f16x8*)(wr + 8 * c);
#pragma unroll
      for (int jj = 0; jj < 4; ++jj) {
        f16x2 hp = {hv[2 * jj], hv[2 * jj + 1]};
        f16x2 wa = {w[0][c][2 * jj], w[0][c][2 * jj + 1]};
        f16x2 wb = {w[1][c][2 * jj], w[1][c][2 * jj + 1]};
        f16x2 wc = {w[2][c][2 * jj], w[2][c][2 * jj + 1]};
        f16x2 wd = {ov[2 * jj], ov[2 * jj + 1]};
        a0 = __builtin_elementwise_fma(wa, hp, a0);
        a1 = __builtin_elementwise_fma(wb, hp, a1);
        a2 = __builtin_elementwise_fma(wc, hp, a2);
        a3 = __builtin_elementwise_fma(wd, hp, a3);
      }
    }
    float r0 = (float)a0[0] + (float)a0[1];
    float r1 = (float)a1[0] + (float)a1[1];
    float r2 = (float)a2[0] + (float)a2[1];
    float r3 = (float)a3[0] + (float)a3[1];
    r0 += __shfl_xor(r0, 1);
    r1 += __shfl_xor(r1, 1);
    r2 += __shfl_xor(r2, 1);
    r3 += __shfl_xor(r3, 1);

    float zi  = bf2f(z0) + r0;
    float zf_ = bf2f(z1) + r1;
    float zg  = bf2f(z2) + r2;
    float zo  = bf2f(z3) + r3;
    float ig = sigm(zi), fg = sigm(zf_), og = sigm(zo);
    float gg = tanhfast(zg);
    float cn = fg * cst + ig * gg;
    float hn = og * tanhfast(cn);
    if (mk != 0) { cst = cn; hst = hn; oprev = hn; }   // mask uniform per block
    if (s == 0) {
      hbuf[(cur ^ 1) * 256 + u] = (_Float16)hst;
      hout[(size_t)(b * 512 + t_cur) * 256 + u] = f2bf(oprev);
    }
    __syncthreads();
    cur ^= 1;
    z0 = nz0; z1 = nz1; z2 = nz2; z3 = nz3; mk = nmk;
  }
}

// ---------------- CRF log-likelihood: 1 wave per batch -----------------------
__global__ __launch_bounds__(64) void crf_kernel(
    const float* __restrict__ logits, const int* __restrict__ targets,
    const int* __restrict__ inputs, const float* __restrict__ trans,
    float* __restrict__ out)
{
  const int b = blockIdx.x, lane = threadIdx.x;
  int slp = 0;
  for (int t = lane; t < 512; t += 64) slp += (inputs[b * 512 + t] != 0) ? 1 : 0;
#pragma unroll
  for (int off = 32; off > 0; off >>= 1) slp += __shfl_xor(slp, off);
  const int seq_len = slp;

  float un = 0.f, bin = 0.f;
  for (int t = lane; t < 512; t += 64) {
    if (t < seq_len)
      un += logits[(size_t)(b * 512 + t) * 20 + targets[b * 512 + t]];
    if (t >= 1 && t < seq_len)
      bin += trans[targets[b * 512 + t - 1] * 20 + targets[b * 512 + t]];
  }
#pragma unroll
  for (int off = 32; off > 0; off >>= 1) {
    un += __shfl_xor(un, off); bin += __shfl_xor(bin, off);
  }

  const int j = (lane < 20) ? lane : 0;
  float tc[20];
#pragma unroll
  for (int i = 0; i < 20; ++i) tc[i] = trans[i * 20 + j];
  float alpha = logits[(size_t)(b * 512) * 20 + j];
  for (int t = 1; t < seq_len; ++t) {
    float emit = logits[(size_t)(b * 512 + t) * 20 + j];
    float tmp[20], mx = -1e30f;
#pragma unroll
    for (int i = 0; i < 20; ++i) {
      float ai = __shfl(alpha, i);
      tmp[i] = ai + tc[i];
      mx = fmaxf(mx, tmp[i]);
    }
    float sum = 0.f;
#pragma unroll
    for (int i = 0; i < 20; ++i) sum += __expf(tmp[i] - mx);
    alpha = mx + __logf(sum) + emit;
  }
  float av = (lane < 20) ? alpha : -1e30f;
  float mx = av;
#pragma unroll
  for (int off = 32; off > 0; off >>= 1) mx = fmaxf(mx, __shfl_xor(mx, off));
  float sum = (lane < 20) ? __expf(av - mx) : 0.f;
#pragma unroll
  for (int off = 32; off > 0; off >>= 1) sum += __shfl_xor(sum, off);
  if (lane == 0) out[b] = un + bin - (mx + __logf(sum));
}

// ---------------- host launcher ---------------------------------------------
extern "C" void kernel_launch(void* const* d_in, const int* in_sizes, int n_in,
                              void* d_out, int out_size, void* d_ws, size_t ws_size,
                              hipStream_t stream)
{
  const int*   inputs  = (const int*)d_in[0];
  const int*   amask   = (const int*)d_in[1];
  const int*   targets = (const int*)d_in[2];
  const float* hid_a   = (const float*)d_in[3];
  const float* hid_b   = (const float*)d_in[4];
  const float* ln1_g   = (const float*)d_in[5];
  const float* ln1_b   = (const float*)d_in[6];
  const float* w1 = (const float*)d_in[7];
  const float* b1 = (const float*)d_in[8];
  const float* w2 = (const float*)d_in[9];
  const float* b2 = (const float*)d_in[10];
  const float* w3 = (const float*)d_in[11];
  const float* b3 = (const float*)d_in[12];
  const float* w4 = (const float*)d_in[13];
  const float* b4 = (const float*)d_in[14];
  const float* ln2_g = (const float*)d_in[15];
  const float* ln2_b = (const float*)d_in[16];
  const float* wx_f = (const float*)d_in[17];
  const float* wh_f = (const float*)d_in[18];
  const float* bfv  = (const float*)d_in[19];
  const float* wx_b = (const float*)d_in[20];
  const float* wh_b = (const float*)d_in[21];
  const float* bbv  = (const float*)d_in[22];
  const float* wd   = (const float*)d_in[23];
  const float* bd   = (const float*)d_in[24];
  const float* trans= (const float*)d_in[25];
  (void)in_sizes; (void)n_in; (void)out_size; (void)ws_size;

  char* ws = (char*)d_ws;
  constexpr size_t SZ_XLN  = (size_t)32768 * 1536 * 2;   // bf16 LN1 out
  constexpr size_t SZ_CONV = (size_t)32768 * 768 * 4;    // f32 conv+relu
  constexpr size_t SZ_CLN  = (size_t)32768 * 768 * 2;    // bf16 LN2 out
  u16*   x_ln      = (u16*)(ws + 0);
  float* conv_relu = (float*)(ws + SZ_XLN);
  u16*   conv_ln   = (u16*)(ws + SZ_XLN + SZ_CONV);
  u16*   zx_f      = (u16*)(ws + 0);                     // reuse x_ln region
  u16*   zx_b      = (u16*)(ws + SZ_XLN);                // reuse conv_relu region
  u16*   hfp       = (u16*)(ws + SZ_XLN + SZ_CONV);      // reuse conv_ln region
  u16*   hbp       = hfp + (size_t)32768 * 256;
  size_t off = SZ_XLN + SZ_CONV + SZ_CLN;
  float* logitsB = (float*)(ws + off); off += (size_t)32768 * 20 * 4;
  u16* wT1 = (u16*)(ws + off); off += (size_t)192 * 1536 * 2;
  u16* wT2 = (u16*)(ws + off); off += (size_t)192 * 3072 * 2;
  u16* wT3 = (u16*)(ws + off); off += (size_t)192 * 4608 * 2;
  u16* wT4 = (u16*)(ws + off); off += (size_t)192 * 6144 * 2;
  u16* wxTf = (u16*)(ws + off); off += (size_t)1024 * 768 * 2;
  u16* wxTb = (u16*)(ws + off); off += (size_t)1024 * 768 * 2;
  _Float16* whTf = (_Float16*)(ws + off); off += (size_t)1024 * 256 * 2;
  _Float16* whTb = (_Float16*)(ws + off); off += (size_t)1024 * 256 * 2;
  u16* wdT = (u16*)(ws + off); off += (size_t)32 * 512 * 2;

  auto tcl = [&](const float* in, void* outp, int K, int Nin, int Nout, int f16o) {
    int tot = K * Nout;
    hipLaunchKernelGGL(transpose_cvt, dim3((tot + 255) / 256), dim3(256), 0, stream,
                       in, outp, K, Nin, Nout, f16o);
  };
  tcl(w1, wT1, 1536, 192, 192, 0);
  tcl(w2, wT2, 3072, 192, 192, 0);
  tcl(w3, wT3, 4608, 192, 192, 0);
  tcl(w4, wT4, 6144, 192, 192, 0);
  tcl(wx_f, wxTf, 768, 1024, 1024, 0);
  tcl(wx_b, wxTb, 768, 1024, 1024, 0);
  tcl(wh_f, whTf, 256, 1024, 1024, 1);
  tcl(wh_b, whTb, 256, 1024, 1024, 1);
  tcl(wd, wdT, 512, 20, 32, 0);

  hipLaunchKernelGGL((ln_kernel<6>), dim3(32768), dim3(256), 0, stream,
                     hid_a, hid_b, ln1_g, ln1_b, x_ln);

  ConvW cw;
  cw.bt[0] = wT1; cw.bt[1] = wT2; cw.bt[2] = wT3; cw.bt[3] = wT4;
  cw.bias[0] = b1; cw.bias[1] = b2; cw.bias[2] = b3; cw.bias[3] = b4;
  hipLaunchKernelGGL(gemm_conv_kernel, dim3(256, 4), dim3(256), 0, stream,
                     x_ln, cw, conv_relu);

  hipLaunchKernelGGL((ln_kernel<3>), dim3(32768), dim3(256), 0, stream,
                     conv_relu, conv_relu, ln2_g, ln2_b, conv_ln);

  hipLaunchKernelGGL(gemm_zx_kernel, dim3(256, 8, 2), dim3(256), 0, stream,
                     conv_ln, wxTf, wxTb, bfv, bbv, zx_f, zx_b);

  // LSTM: 136 KB o-gate weights + 1 KB h double-buffer in dynamic LDS
  const int lstm_lds = 512 * 136 * 2 + 2 * 256 * 2;
  static bool attr_set = []() { return true; }();  // no-op; attribute set below every call (idempotent)
  (void)attr_set;
  hipFuncSetAttribute((const void*)lstm_kernel,
                      hipFuncAttributeMaxDynamicSharedMemorySize, lstm_lds);
  hipLaunchKernelGGL(lstm_kernel, dim3(128), dim3(512), lstm_lds, stream,
                     zx_f, zx_b, whTf, whTb, amask, hfp, hbp);

  hipLaunchKernelGGL(gemm_logits_kernel, dim3(256), dim3(256), 0, stream,
                     hfp, hbp, wdT, bd, logitsB);

  hipLaunchKernelGGL(crf_kernel, dim3(64), dim3(64), 0, stream,
                     logitsB, targets, inputs, trans, (float*)d_out);
}